// Round 12
// baseline (313.734 us; speedup 1.0000x reference)
//
#include <hip/hip_runtime.h>
#include <math.h>

#define RING_CH 6          // chunks per group
#define CH_F4   256        // float4 slots per chunk (4 rows x 64)
#define SLOT_F4 (RING_CH * CH_F4)   // 1536 float4 per ring slot
#define TABN    2048
#define BUFM    4095

// ---------------------------------------------------------------------------
// Phase 1: natural cubic spline coefficients, 3 channels. Single block.
// Also initializes per-segment min-z table.
// ---------------------------------------------------------------------------
__global__ void spline_setup(const float* __restrict__ delay_in,
                             const float* __restrict__ raw,
                             double* __restrict__ coef,
                             int* __restrict__ segmin,
                             int nseg, int nf) {
    extern __shared__ double smem[];
    double* xch = smem;           // 3*nf
    double* cp  = xch + 3 * nf;   // nf
    double* kk  = cp + nf;        // 3*nf

    int tid = threadIdx.x;
    for (int i = tid; i < nseg; i += blockDim.x) segmin[i] = 0x7fffffff;

    for (int i = tid; i < nf; i += blockDim.x) {
        double s0 = 1.0 / (1.0 + exp(-(double)raw[2 * i + 0]));
        double s1 = 1.0 / (1.0 + exp(-(double)raw[2 * i + 1]));
        double ss = s0 + s1;
        xch[0 * nf + i] = (double)delay_in[i];
        xch[1 * nf + i] = s0 / ss;
        xch[2 * nf + i] = s1 / ss;
    }
    __syncthreads();

    if (tid == 0) {
        cp[0] = 0.5;
        for (int i = 1; i < nf; ++i) {
            double d = (i == nf - 1) ? 2.0 : 4.0;
            cp[i] = 1.0 / (d - cp[i - 1]);
        }
    }
    __syncthreads();

    if (tid < 3) {
        const double* x = xch + tid * nf;
        double* k = kk + tid * nf;
        double hinv = (double)(nf - 1);
        double prev = 0.0;
        for (int j = 0; j < nf; ++j) {
            double r = 0.0;
            if (j < nf - 1) r += 3.0 * hinv * (x[j + 1] - x[j]);
            if (j > 0)      r += 3.0 * hinv * (x[j] - x[j - 1]);
            double dp = (r - prev) * cp[j];
            k[j] = dp;
            prev = dp;
        }
        for (int j = nf - 2; j >= 0; --j) k[j] = k[j] - cp[j] * k[j + 1];
    }
    __syncthreads();

    int nint = nf - 1;
    double hinv = (double)(nf - 1);
    for (int w = tid; w < 3 * nint; w += blockDim.x) {
        int ch = w / nint;
        int i = w - ch * nint;
        const double* x = xch + ch * nf;
        const double* k = kk + ch * nf;
        double dx3 = 3.0 * (x[i + 1] - x[i]);
        double two_c   = (2.0 * dx3 * hinv - 4.0 * k[i] - 2.0 * k[i + 1]) * hinv;
        double three_d = (-2.0 * dx3 * hinv + 3.0 * (k[i] + k[i + 1])) * hinv * hinv;
        double* C = coef + (size_t)(ch * nint + i) * 4;
        C[0] = x[i];
        C[1] = k[i];
        C[2] = 0.5 * two_c;
        C[3] = three_d * (1.0 / 3.0);
    }
}

// ---------------------------------------------------------------------------
// Phase 2: per-sample spline eval -> {g1, g2, g3, s3} one float4.
// s3 = (t - z - 3) & 4095 : base slot of 3 contiguous history reads in the
// 4096-slot scan buffer (slots 4096/4097 shadow 0/1).
// Per-1024-segment min z via one atomic per wave (wave never crosses a
// segment boundary: 64 | 1024). Pads [n, nTot) with zeros.
// ---------------------------------------------------------------------------
__global__ void eval_kernel(const double* __restrict__ coef,
                            float4* __restrict__ gx,
                            int* __restrict__ segmin,
                            int n, int nTot, int nf) {
    int j = blockIdx.x * blockDim.x + threadIdx.x;
    if (j >= nTot) return;
    if (j >= n) { gx[j] = make_float4(0.f, 0.f, 0.f, 0.f); return; }

    double u = (double)j / (double)(n - 1);
    double nfm1 = (double)(nf - 1);
    int idx = (int)(u * nfm1);
    if (idx > nf - 2) idx = nf - 2;
    if (idx < 0) idx = 0;
    double tknot = (double)idx / nfm1;
    if (u < tknot && idx > 0) {
        idx--; tknot = (double)idx / nfm1;
    } else {
        double tnext = (double)(idx + 1) / nfm1;
        if (u >= tnext && idx < nf - 2) { idx++; tknot = tnext; }
    }
    double f = u - tknot;

    int nint = nf - 1;
    const double* C0 = coef + (size_t)(0 * nint + idx) * 4;
    const double* C1 = coef + (size_t)(1 * nint + idx) * 4;
    const double* C2 = coef + (size_t)(2 * nint + idx) * 4;
    double dly = C0[0] + f * (C0[1] + f * (C0[2] + f * C0[3]));
    double b1d = C1[0] + f * (C1[1] + f * (C1[2] + f * C1[3]));
    double b2d = C2[0] + f * (C2[1] + f * (C2[2] + f * C2[3]));

    double zf = floor(dly);
    int z = (int)zf;
    float alfa = (float)(dly - zf);
    float b1 = (float)b1d, b2 = (float)b2d;
    float g1 = b1 * (1.0f - alfa);
    float g2 = b1 * alfa + b2 * (1.0f - alfa);
    float g3 = b2 * alfa;

    int s3 = (j - z - 3) & BUFM;
    gx[j] = make_float4(g1, g2, g3, __uint_as_float((unsigned int)s3));

    int wmin = z;
    #pragma unroll
    for (int o = 32; o > 0; o >>= 1) wmin = min(wmin, __shfl_down(wmin, o, 64));
    if ((threadIdx.x & 63) == 0) atomicMin(&segmin[j >> 10], wmin);
}

// ---------------------------------------------------------------------------
// Phase 3: producer/consumer with VARIABLE per-segment chunk length.
// Plan (prologue, all 128 threads): thread s handles 1024-sample segment s:
// Dmax = clamp(segmin[s]+1, 4, 256); k = ceil(L/Dmax); len = ceil(L/k).
// Chunks never cross segment boundaries => all history reads of a chunk
// target positions < chunk base. Chunk table in LDS, 8-stride per group of
// 6 (entries 6,7 pad), entry = (base<<9)|len, pad entries = (n<<9)|0.
// Consumer (wave 0): per group, 6 chunks x 4 rows; per chunk: 12 history
// ds_read + 12 FMA + masked writes; next chunk's stream prefetched during
// body. Pure LDS.
// Producer (wave 1): per group: exactly 24 stores (y-offload of group g-1,
// sink-padded) + 24 global_load_lds (group g+2 -> 4-deep ring) then counted
// s_waitcnt vmcnt(48) => group g+1 resident; loads stay in flight across
// the raw s_barrier (round-11 validated pattern).
// buf = 4096 circular (group span <= 1536; producer-read/consumer-write
// distance <= 3071) + 2 shadow (mirror 0/1) + 2 dummy.
// ---------------------------------------------------------------------------
__global__ void __launch_bounds__(128, 1)
scan_kernel(const float4* __restrict__ gx,
            const int* __restrict__ segmin,
            const float* __restrict__ exc,
            float* __restrict__ y,
            float* __restrict__ sink,
            int n, int burst) {
    __shared__ float buf[4100];
    __shared__ float excl[2048];
    __shared__ __align__(16) int chunkTab[TABN];
    __shared__ float4 ring[4 * SLOT_F4];   // 96 KB
    __shared__ int wtot[2];

    const int tid = threadIdx.x;
    for (int i = tid; i < 4100; i += 128) buf[i] = 0.0f;
    for (int i = tid; i < 2048; i += 128) excl[i] = (i < burst) ? exc[i] : 0.0f;
    for (int i = tid; i < TABN; i += 128) chunkTab[i] = (n << 9);

    // ---- plan: build chunk table ----
    int nseg = (n + 1023) >> 10;
    int kcnt = 0, clen = 0, L = 0;
    if (tid < nseg && tid < 128) {
        L = n - (tid << 10); if (L > 1024) L = 1024;
        int Dm = segmin[tid] + 1;
        if (Dm > 256) Dm = 256;
        if (Dm < 4) Dm = 4;
        kcnt = (L + Dm - 1) / Dm;
        clen = (L + kcnt - 1) / kcnt;
    }
    int pre = kcnt;
    #pragma unroll
    for (int d = 1; d < 64; d <<= 1) {
        int o = __shfl_up(pre, d, 64);
        if ((tid & 63) >= d) pre += o;
    }
    if ((tid & 63) == 63) wtot[tid >> 6] = pre;
    __syncthreads();
    int excl0 = pre - kcnt + ((tid >= 64) ? wtot[0] : 0);
    int total = wtot[0] + wtot[1];
    for (int c = 0; c < kcnt; ++c) {
        int i = excl0 + c;
        int pos = (i / 6) * 8 + (i % 6);
        int b = (tid << 10) + c * clen;
        int l = L - c * clen; if (l > clen) l = clen;
        chunkTab[pos] = (b << 9) | l;
    }
    __syncthreads();

    const int nG = (__builtin_amdgcn_readfirstlane(total) + RING_CH - 1) / RING_CH;

    int sA = 0, sB = 0, sC = 0;   // producer rolling starts: g-1, g, g+1

#define GLL(gsrc, ldst)                                                       \
    __builtin_amdgcn_global_load_lds(                                         \
        (const __attribute__((address_space(1))) void*)(gsrc),                \
        (__attribute__((address_space(3))) void*)(ldst), 16, 0, 0)

#define RFL(v) __builtin_amdgcn_readfirstlane(v)

    // ---- prologue: producer fills groups 0,1; full drain ----
    if (tid >= 64) {
        int lane = tid - 64;
        int4 ea = *(const int4*)&chunkTab[0];
        int4 eb = *(const int4*)&chunkTab[4];
        int4 ec = *(const int4*)&chunkTab[8];
        int4 ed = *(const int4*)&chunkTab[12];
        int b0[6] = { RFL(ea.x) >> 9, RFL(ea.y) >> 9, RFL(ea.z) >> 9,
                      RFL(ea.w) >> 9, RFL(eb.x) >> 9, RFL(eb.y) >> 9 };
        int b1[6] = { RFL(ec.x) >> 9, RFL(ec.y) >> 9, RFL(ec.z) >> 9,
                      RFL(ec.w) >> 9, RFL(ed.x) >> 9, RFL(ed.y) >> 9 };
        #pragma unroll
        for (int c = 0; c < 6; ++c) {
            #pragma unroll
            for (int r = 0; r < 4; ++r) {
                GLL(gx + b0[c] + r * 64 + lane, &ring[0 * SLOT_F4 + c * CH_F4 + r * 64]);
                GLL(gx + b1[c] + r * 64 + lane, &ring[1 * SLOT_F4 + c * CH_F4 + r * 64]);
            }
        }
        sA = 0; sB = b0[0]; sC = b1[0];
    }
    __syncthreads();   // full vmcnt drain: groups 0,1 resident

    // consumer body for one chunk (4 rows)
#define CBODY(q0, q1, q2, q3, E)                                              \
    {                                                                         \
        int bc = (E) >> 9, lc = (E) & 511;                                    \
        int t0 = bc + tid;                                                    \
        unsigned u0 = __float_as_uint((q0).w);                                \
        unsigned u1 = __float_as_uint((q1).w);                                \
        unsigned u2 = __float_as_uint((q2).w);                                \
        unsigned u3 = __float_as_uint((q3).w);                                \
        float a3 = buf[u0], a2 = buf[u0 + 1], a1 = buf[u0 + 2];               \
        float b3 = buf[u1], b2 = buf[u1 + 1], b1 = buf[u1 + 2];               \
        float c3 = buf[u2], c2 = buf[u2 + 1], c1 = buf[u2 + 2];               \
        float d3 = buf[u3], d2 = buf[u3 + 1], d1 = buf[u3 + 2];               \
        float x0 = 0.f, x1 = 0.f, x2 = 0.f, x3 = 0.f;                         \
        if (bc < burst) {                                                     \
            x0 = (t0 < burst) ? excl[t0 & 2047] : 0.0f;                       \
            x1 = (t0 + 64 < burst) ? excl[(t0 + 64) & 2047] : 0.0f;           \
            x2 = (t0 + 128 < burst) ? excl[(t0 + 128) & 2047] : 0.0f;         \
            x3 = (t0 + 192 < burst) ? excl[(t0 + 192) & 2047] : 0.0f;         \
        }                                                                     \
        float y0 = fmaf((q0).x, a1, x0);                                      \
        y0 = fmaf((q0).y, a2, y0); y0 = fmaf((q0).z, a3, y0);                 \
        float y1 = fmaf((q1).x, b1, x1);                                      \
        y1 = fmaf((q1).y, b2, y1); y1 = fmaf((q1).z, b3, y1);                 \
        float y2 = fmaf((q2).x, c1, x2);                                      \
        y2 = fmaf((q2).y, c2, y2); y2 = fmaf((q2).z, c3, y2);                 \
        float y3 = fmaf((q3).x, d1, x3);                                      \
        y3 = fmaf((q3).y, d2, y3); y3 = fmaf((q3).z, d3, y3);                 \
        bool o0 = tid < lc, o1 = 64 + tid < lc;                               \
        bool o2 = 128 + tid < lc, o3 = 192 + tid < lc;                        \
        int w0 = t0 & BUFM, w1 = (t0 + 64) & BUFM;                            \
        int w2 = (t0 + 128) & BUFM, w3 = (t0 + 192) & BUFM;                   \
        buf[o0 ? w0 : 4098] = y0;                                             \
        buf[o1 ? w1 : 4099] = y1;                                             \
        buf[o2 ? w2 : 4098] = y2;                                             \
        buf[o3 ? w3 : 4099] = y3;                                             \
        buf[(o0 && w0 < 2) ? 4096 + w0 : 4098] = y0;                          \
        buf[(o1 && w1 < 2) ? 4096 + w1 : 4099] = y1;                          \
        buf[(o2 && w2 < 2) ? 4096 + w2 : 4098] = y2;                          \
        buf[(o3 && w3 < 2) ? 4096 + w3 : 4099] = y3;                          \
    }

    for (int g = 0; g < nG; ++g) {
        if (tid >= 64) {
            int lane = tid - 64;
            // entries of group g+2
            int4 ea = *(const int4*)&chunkTab[(g + 2) * 8];
            int4 eb = *(const int4*)&chunkTab[(g + 2) * 8 + 4];
            int nb[6] = { RFL(ea.x) >> 9, RFL(ea.y) >> 9, RFL(ea.z) >> 9,
                          RFL(ea.w) >> 9, RFL(eb.x) >> 9, RFL(eb.y) >> 9 };
            // (1) exactly 24 stores: y-offload of group g-1
            int span = sB - sA;
            float vals[24];
            #pragma unroll
            for (int kk = 0; kk < 24; ++kk)
                vals[kk] = buf[(sA + kk * 64 + lane) & BUFM];
            #pragma unroll
            for (int kk = 0; kk < 24; ++kk) {
                int off = kk * 64 + lane;
                bool ok = (g > 0) && (off < span);
                float* dst = ok ? (y + sA + off) : (sink + off);
                *dst = vals[kk];
            }
            // (2) exactly 24 loads: prefetch group g+2
            int slot = (g + 2) & 3;
            #pragma unroll
            for (int c = 0; c < 6; ++c) {
                #pragma unroll
                for (int r = 0; r < 4; ++r)
                    GLL(gx + nb[c] + r * 64 + lane,
                        &ring[slot * SLOT_F4 + c * CH_F4 + r * 64]);
            }
            // (3) counted wait: group g+1's loads (48 ops back) resident
            asm volatile("s_waitcnt vmcnt(48)" ::: "memory");
            sA = sB; sB = sC; sC = nb[0];
        } else {
            int4 ea = *(const int4*)&chunkTab[g * 8];
            int4 eb = *(const int4*)&chunkTab[g * 8 + 4];
            int e0 = RFL(ea.x), e1 = RFL(ea.y), e2 = RFL(ea.z);
            int e3 = RFL(ea.w), e4 = RFL(eb.x), e5 = RFL(eb.y);
            const float4* R = ring + (g & 3) * SLOT_F4;
            float4 q0 = R[0 * CH_F4 + tid];
            float4 q1 = R[0 * CH_F4 + 64 + tid];
            float4 q2 = R[0 * CH_F4 + 128 + tid];
            float4 q3 = R[0 * CH_F4 + 192 + tid];
            float4 n0, n1, n2, n3;
            // chunk 0 (prefetch 1)
            n0 = R[1 * CH_F4 + tid];       n1 = R[1 * CH_F4 + 64 + tid];
            n2 = R[1 * CH_F4 + 128 + tid]; n3 = R[1 * CH_F4 + 192 + tid];
            CBODY(q0, q1, q2, q3, e0)
            q0 = n0; q1 = n1; q2 = n2; q3 = n3;
            // chunk 1 (prefetch 2)
            n0 = R[2 * CH_F4 + tid];       n1 = R[2 * CH_F4 + 64 + tid];
            n2 = R[2 * CH_F4 + 128 + tid]; n3 = R[2 * CH_F4 + 192 + tid];
            CBODY(q0, q1, q2, q3, e1)
            q0 = n0; q1 = n1; q2 = n2; q3 = n3;
            // chunk 2 (prefetch 3)
            n0 = R[3 * CH_F4 + tid];       n1 = R[3 * CH_F4 + 64 + tid];
            n2 = R[3 * CH_F4 + 128 + tid]; n3 = R[3 * CH_F4 + 192 + tid];
            CBODY(q0, q1, q2, q3, e2)
            q0 = n0; q1 = n1; q2 = n2; q3 = n3;
            // chunk 3 (prefetch 4)
            n0 = R[4 * CH_F4 + tid];       n1 = R[4 * CH_F4 + 64 + tid];
            n2 = R[4 * CH_F4 + 128 + tid]; n3 = R[4 * CH_F4 + 192 + tid];
            CBODY(q0, q1, q2, q3, e3)
            q0 = n0; q1 = n1; q2 = n2; q3 = n3;
            // chunk 4 (prefetch 5)
            n0 = R[5 * CH_F4 + tid];       n1 = R[5 * CH_F4 + 64 + tid];
            n2 = R[5 * CH_F4 + 128 + tid]; n3 = R[5 * CH_F4 + 192 + tid];
            CBODY(q0, q1, q2, q3, e4)
            q0 = n0; q1 = n1; q2 = n2; q3 = n3;
            // chunk 5
            CBODY(q0, q1, q2, q3, e5)
        }
        asm volatile("s_waitcnt lgkmcnt(0)" ::: "memory");
        __builtin_amdgcn_sched_barrier(0);
        __builtin_amdgcn_s_barrier();
        __builtin_amdgcn_sched_barrier(0);
    }

    __syncthreads();
    // epilogue: offload last group's outputs (all 128 threads)
    {
        int startL = chunkTab[(nG - 1) * 8] >> 9;
        for (int t = startL + tid; t < n; t += 128) y[t] = buf[t & BUFM];
    }
#undef CBODY
#undef GLL
#undef RFL
}

// ---------------------------------------------------------------------------
extern "C" void kernel_launch(void* const* d_in, const int* in_sizes, int n_in,
                              void* d_out, int out_size, void* d_ws, size_t ws_size,
                              hipStream_t stream) {
    const float* delay = (const float*)d_in[0];
    const float* raw   = (const float*)d_in[1];
    const float* exc   = (const float*)d_in[2];
    int nf = in_sizes[0];
    int burst = in_sizes[2];
    if (burst > 2048) burst = 2048;
    int n = out_size;
    int nseg = (n + 1023) >> 10;
    int nTot = n + 2048;   // pad covers producer prefetch overshoot

    char* ws = (char*)d_ws;
    size_t coefBytes = (size_t)3 * (nf - 1) * 4 * sizeof(double);
    size_t off = (coefBytes + 255) & ~(size_t)255;
    double* coef = (double*)ws;
    int* segmin = (int*)(ws + off);
    off += 1024;                       // 128 segments + pad
    float* sink = (float*)(ws + off);
    off += 8192;                       // 1536 floats + pad
    float4* gxa = (float4*)(ws + off);

    size_t shmem = (size_t)(7 * nf) * sizeof(double);
    spline_setup<<<1, 64, shmem, stream>>>(delay, raw, coef, segmin, nseg, nf);
    eval_kernel<<<(nTot + 255) / 256, 256, 0, stream>>>(coef, gxa, segmin, n, nTot, nf);
    scan_kernel<<<1, 128, 0, stream>>>(gxa, segmin, exc, (float*)d_out, sink, n, burst);
}

// Round 13
// 192.343 us; speedup vs baseline: 1.6311x; 1.6311x over previous
//
#include <hip/hip_runtime.h>
#include <math.h>

// ---------------------------------------------------------------------------
// Phase 1: natural cubic spline coefficients, 3 channels. Single block.
// ---------------------------------------------------------------------------
__global__ void spline_setup(const float* __restrict__ delay_in,
                             const float* __restrict__ raw,
                             double* __restrict__ coef,
                             int* __restrict__ minz,
                             int nf) {
    extern __shared__ double smem[];
    double* xch = smem;           // 3*nf
    double* cp  = xch + 3 * nf;   // nf
    double* kk  = cp + nf;        // 3*nf

    int tid = threadIdx.x;
    if (tid == 0) *minz = 0x7fffffff;

    for (int i = tid; i < nf; i += blockDim.x) {
        double s0 = 1.0 / (1.0 + exp(-(double)raw[2 * i + 0]));
        double s1 = 1.0 / (1.0 + exp(-(double)raw[2 * i + 1]));
        double ss = s0 + s1;
        xch[0 * nf + i] = (double)delay_in[i];
        xch[1 * nf + i] = s0 / ss;
        xch[2 * nf + i] = s1 / ss;
    }
    __syncthreads();

    if (tid == 0) {
        cp[0] = 0.5;
        for (int i = 1; i < nf; ++i) {
            double d = (i == nf - 1) ? 2.0 : 4.0;
            cp[i] = 1.0 / (d - cp[i - 1]);
        }
    }
    __syncthreads();

    if (tid < 3) {
        const double* x = xch + tid * nf;
        double* k = kk + tid * nf;
        double hinv = (double)(nf - 1);
        double prev = 0.0;
        for (int j = 0; j < nf; ++j) {
            double r = 0.0;
            if (j < nf - 1) r += 3.0 * hinv * (x[j + 1] - x[j]);
            if (j > 0)      r += 3.0 * hinv * (x[j] - x[j - 1]);
            double dp = (r - prev) * cp[j];
            k[j] = dp;
            prev = dp;
        }
        for (int j = nf - 2; j >= 0; --j) k[j] = k[j] - cp[j] * k[j + 1];
    }
    __syncthreads();

    int nint = nf - 1;
    double hinv = (double)(nf - 1);
    for (int w = tid; w < 3 * nint; w += blockDim.x) {
        int ch = w / nint;
        int i = w - ch * nint;
        const double* x = xch + ch * nf;
        const double* k = kk + ch * nf;
        double dx3 = 3.0 * (x[i + 1] - x[i]);
        double two_c   = (2.0 * dx3 * hinv - 4.0 * k[i] - 2.0 * k[i + 1]) * hinv;
        double three_d = (-2.0 * dx3 * hinv + 3.0 * (k[i] + k[i + 1])) * hinv * hinv;
        double* C = coef + (size_t)(ch * nint + i) * 4;
        C[0] = x[i];
        C[1] = k[i];
        C[2] = 0.5 * two_c;
        C[3] = three_d * (1.0 / 3.0);
    }
}

// ---------------------------------------------------------------------------
// Phase 2: per-sample spline eval -> {g1, g2, g3, s3} one float4.
// s3 = (t - z - 3) & 2047 : base slot of 3 contiguous history reads in the
// 2048-slot scan buffer (slots 2048/2049 shadow 0/1).
// Global min z via one atomic per wave. Pads [n, nTot) with zeros.
// ---------------------------------------------------------------------------
__global__ void eval_kernel(const double* __restrict__ coef,
                            float4* __restrict__ gx,
                            int* __restrict__ minz,
                            int n, int nTot, int nf) {
    int j = blockIdx.x * blockDim.x + threadIdx.x;
    if (j >= nTot) return;
    if (j >= n) { gx[j] = make_float4(0.f, 0.f, 0.f, 0.f); return; }

    double u = (double)j / (double)(n - 1);
    double nfm1 = (double)(nf - 1);
    int idx = (int)(u * nfm1);
    if (idx > nf - 2) idx = nf - 2;
    if (idx < 0) idx = 0;
    double tknot = (double)idx / nfm1;
    if (u < tknot && idx > 0) {
        idx--; tknot = (double)idx / nfm1;
    } else {
        double tnext = (double)(idx + 1) / nfm1;
        if (u >= tnext && idx < nf - 2) { idx++; tknot = tnext; }
    }
    double f = u - tknot;

    int nint = nf - 1;
    const double* C0 = coef + (size_t)(0 * nint + idx) * 4;
    const double* C1 = coef + (size_t)(1 * nint + idx) * 4;
    const double* C2 = coef + (size_t)(2 * nint + idx) * 4;
    double dly = C0[0] + f * (C0[1] + f * (C0[2] + f * C0[3]));
    double b1d = C1[0] + f * (C1[1] + f * (C1[2] + f * C1[3]));
    double b2d = C2[0] + f * (C2[1] + f * (C2[2] + f * C2[3]));

    double zf = floor(dly);
    int z = (int)zf;
    float alfa = (float)(dly - zf);
    float b1 = (float)b1d, b2 = (float)b2d;
    float g1 = b1 * (1.0f - alfa);
    float g2 = b1 * alfa + b2 * (1.0f - alfa);
    float g3 = b2 * alfa;

    int s3 = (j - z - 3) & 2047;
    gx[j] = make_float4(g1, g2, g3, __uint_as_float((unsigned int)s3));

    int wmin = z;
    #pragma unroll
    for (int o = 32; o > 0; o >>= 1) wmin = min(wmin, __shfl_down(wmin, o, 64));
    if ((threadIdx.x & 63) == 0) atomicMin(minz, wmin);
}

// ---------------------------------------------------------------------------
// Phase 3: producer/consumer, FIXED D=64 (legal: minz ~100 >= 63, so every
// history read of chunk c targets positions < c*64). Group = 16 chunks =
// 1024 samples. Round-12 post-mortem: time ~ 210cy x row-count; so (a) 100%
// lane-full rows (2048 total, -21% vs R11), (b) minimal row body: 1 stream
// ds_read_b128 (immediate-offset from one base) + 3 history ds_read (one
// vaddr, offset 0/4/8) + 3 FMA + 1 ds_write (immediate offset). No masks,
// no shadow select (compile-time c==0 case), no chunk table.
// Producer per group: exactly 16 y-offload stores (group g-1; sink for g=0)
// + 16 global_load_lds (group g+2 -> 4-deep ring) + counted vmcnt(32)
// (oldest 32 drained = prev group's ops incl. g+1's loads). Loads stay in
// flight across the raw s_barrier (R11-validated).
// buf = 2048 circular + 2 shadow; group span 1024 => producer reads group
// g-1's slots exactly one 1024-window behind consumer writes: distance <
// 2048, no collision.
// ---------------------------------------------------------------------------
__global__ void __launch_bounds__(128, 1)
scan_kernel(const float4* __restrict__ gx,
            const int* __restrict__ minz,
            const float* __restrict__ exc,
            float* __restrict__ y,
            float* __restrict__ sink,
            int n, int burst) {
    __shared__ float buf[2052];          // 2048 circular + 2 shadow + pad
    __shared__ float excl[2048];
    __shared__ float4 ring[4 * 1024];    // 4 group-slots x 16 chunks x 64 = 64 KB

    const int tid = threadIdx.x;
    for (int i = tid; i < 2052; i += 128) buf[i] = 0.0f;
    for (int i = tid; i < 2048; i += 128) excl[i] = (i < burst) ? exc[i] : 0.0f;

    int mz = __builtin_amdgcn_readfirstlane(*minz);
    const int nFull = n >> 10;

#define GLL(gsrc, ldst)                                                       \
    __builtin_amdgcn_global_load_lds(                                         \
        (const __attribute__((address_space(1))) void*)(gsrc),                \
        (__attribute__((address_space(3))) void*)(ldst), 16, 0, 0)

    // ---------------- fallback (never taken for this data: mz ~ 100) -------
    if (mz < 63 || nFull < 2) {
        __syncthreads();
        if (tid < 64) {
            int Df = mz + 1;
            if (Df > 64) Df = 64;
            if (Df < 1) Df = 1;
            for (int base = 0; base < n; base += Df) {
                int t = base + tid;
                bool ok = (tid < Df) && (t < n);
                float4 q = ok ? gx[t] : make_float4(0.f, 0.f, 0.f, 0.f);
                unsigned u = __float_as_uint(q.w);
                float a3 = buf[u], a2 = buf[u + 1], a1 = buf[u + 2];
                float x = (t < burst) ? excl[t & 2047] : 0.0f;
                float y0 = fmaf(q.x, a1, x);
                y0 = fmaf(q.y, a2, y0);
                y0 = fmaf(q.z, a3, y0);
                if (ok) {
                    int w = t & 2047;
                    buf[w] = y0;
                    if (w < 2) buf[2048 + w] = y0;
                    y[t] = y0;
                }
            }
        }
        return;
    }

    // ---------------- prologue: producer fills groups 0,1 ------------------
    if (tid >= 64) {
        int lane = tid - 64;
        #pragma unroll
        for (int c = 0; c < 16; ++c)
            GLL(gx + (c << 6) + lane, &ring[(c << 6)]);
        #pragma unroll
        for (int c = 0; c < 16; ++c)
            GLL(gx + 1024 + (c << 6) + lane, &ring[1024 + (c << 6)]);
    }
    __syncthreads();   // full drain: groups 0,1 resident; buf/excl visible

    for (int g = 0; g < nFull; ++g) {
        if (tid >= 64) {
            // ---------------- producer ----------------
            int lane = tid - 64;
            int prevw = ((g - 1) & 1) << 10;       // buf window of group g-1
            int prev = (g - 1) << 10;
            float vals[16];
            #pragma unroll
            for (int k = 0; k < 16; ++k)
                vals[k] = buf[prevw + (k << 6) + lane];
            #pragma unroll
            for (int k = 0; k < 16; ++k) {
                int off = (k << 6) + lane;
                float* dst = (g > 0) ? (y + prev + off) : (sink + off);
                *dst = vals[k];                    // exactly 16 stores
            }
            int pb = (g + 2) << 10;
            int slot = (g + 2) & 3;
            #pragma unroll
            for (int c = 0; c < 16; ++c)
                GLL(gx + pb + (c << 6) + lane, &ring[(slot << 10) + (c << 6)]);
            // counted wait: drains prev group's 32 ops (incl. g+1's loads)
            asm volatile("s_waitcnt vmcnt(32)" ::: "memory");
        } else {
            // ---------------- consumer (pure LDS) ----------------
            const float4* Rp = ring + ((g & 3) << 10);
            int wb = ((g & 1) << 10) + tid;        // buf write base (c=0)
            int gb = g << 10;
            bool wx = (gb < burst);                // uniform; first 2 groups
            float4 q = Rp[tid];
            #pragma unroll
            for (int c = 0; c < 16; ++c) {
                float4 qn;
                if (c < 15) qn = Rp[((c + 1) << 6) + tid];
                unsigned u = __float_as_uint(q.w);
                float a3 = buf[u], a2 = buf[u + 1], a1 = buf[u + 2];
                float x = 0.0f;
                if (wx) {
                    int t = gb + (c << 6) + tid;
                    x = (t < burst) ? excl[t & 2047] : 0.0f;
                }
                float y0 = fmaf(q.x, a1, x);
                y0 = fmaf(q.y, a2, y0);
                y0 = fmaf(q.z, a3, y0);
                buf[wb + (c << 6)] = y0;
                if (c == 0 && (g & 1) == 0 && tid < 2) buf[2048 + tid] = y0;
                q = qn;
            }
        }
        // raw barrier: producer's g+2 loads stay in flight across it
        asm volatile("s_waitcnt lgkmcnt(0)" ::: "memory");
        __builtin_amdgcn_sched_barrier(0);
        __builtin_amdgcn_s_barrier();
        __builtin_amdgcn_sched_barrier(0);
    }

    __syncthreads();   // drain everything before epilogue

    if (tid >= 64) {
        // offload group nFull-1 (final in buf)
        int lane = tid - 64;
        int start = (nFull - 1) << 10;
        #pragma unroll
        for (int k = 0; k < 16; ++k) {
            int t = start + (k << 6) + lane;
            if (t < n) y[t] = buf[t & 2047];
        }
    } else {
        // tail samples [nFull<<10, n): direct-global, masked (empty when 1024|n)
        for (int base = nFull << 10; base < n; base += 64) {
            int t = base + tid;
            bool ok = (t < n);
            float4 q = ok ? gx[t] : make_float4(0.f, 0.f, 0.f, 0.f);
            unsigned u = __float_as_uint(q.w);
            float a3 = buf[u], a2 = buf[u + 1], a1 = buf[u + 2];
            float x = (t < burst) ? excl[t & 2047] : 0.0f;
            float y0 = fmaf(q.x, a1, x);
            y0 = fmaf(q.y, a2, y0);
            y0 = fmaf(q.z, a3, y0);
            if (ok) {
                int w = t & 2047;
                buf[w] = y0;
                if (w < 2) buf[2048 + w] = y0;
                y[t] = y0;
            }
        }
    }
#undef GLL
}

// ---------------------------------------------------------------------------
extern "C" void kernel_launch(void* const* d_in, const int* in_sizes, int n_in,
                              void* d_out, int out_size, void* d_ws, size_t ws_size,
                              hipStream_t stream) {
    const float* delay = (const float*)d_in[0];
    const float* raw   = (const float*)d_in[1];
    const float* exc   = (const float*)d_in[2];
    int nf = in_sizes[0];
    int burst = in_sizes[2];
    if (burst > 2048) burst = 2048;
    int n = out_size;
    int nTot = n + 4096;   // pad covers producer prefetch overshoot (2 groups)

    char* ws = (char*)d_ws;
    size_t coefBytes = (size_t)3 * (nf - 1) * 4 * sizeof(double);
    size_t off = (coefBytes + 255) & ~(size_t)255;
    double* coef = (double*)ws;
    int* minz = (int*)(ws + off);
    off += 256;
    float* sink = (float*)(ws + off);
    off += 4096;
    float4* gxa = (float4*)(ws + off);

    size_t shmem = (size_t)(7 * nf) * sizeof(double);
    spline_setup<<<1, 64, shmem, stream>>>(delay, raw, coef, minz, nf);
    eval_kernel<<<(nTot + 255) / 256, 256, 0, stream>>>(coef, gxa, minz, n, nTot, nf);
    scan_kernel<<<1, 128, 0, stream>>>(gxa, minz, exc, (float*)d_out, sink, n, burst);
}